// Round 5
// baseline (167.361 us; speedup 1.0000x reference)
//
#include <hip/hip_runtime.h>
#include <hip/hip_bf16.h>

#define N_NODES 10000
#define N_EDGES 640000
#define CH 128
#define KN 118   // node_feat inner dim

typedef _Float16 h2 __attribute__((ext_vector_type(2)));
typedef _Float16 h8 __attribute__((ext_vector_type(8)));

#define H2_OF(v, k) __builtin_shufflevector((v), (v), 2 * (k), 2 * (k) + 1)

// K1: fold weights. M[mat][i][c] = sum_j Wn[i][j] * Wa1[mat*128 + j][c]
//     V[mat][c]    = sum_j bn[j]  * Wa1[mat*128 + j][c]  (+ ba1[c] for mat==1)
// Extra block (mat==2): convert w2 -> f16 table for k3.
__global__ __launch_bounds__(128) void k1_weights(
    const float* __restrict__ Wn, const float* __restrict__ bn,
    const float* __restrict__ Wa1, const float* __restrict__ ba1,
    const float* __restrict__ w2, float* __restrict__ M,
    float* __restrict__ V, _Float16* __restrict__ w2h) {
  int c = threadIdx.x;                 // 0..127
  int mat = blockIdx.x / 119;          // 0: src-half, 1: dst-half, 2: w2 conv
  int i = blockIdx.x % 119;            // 0..117 weight rows, 118 = bias row
  if (mat == 2) {
    w2h[c] = (_Float16)w2[c];
    return;
  }
  const float* B = Wa1 + mat * CH * CH;
  const float* a = (i < KN) ? (Wn + i * CH) : bn;
  float acc = 0.f;
#pragma unroll 8
  for (int j = 0; j < CH; ++j) acc = fmaf(a[j], B[j * CH + c], acc);
  if (i < KN) {
    M[(mat * KN + i) * CH + c] = acc;
  } else {
    if (mat == 1) acc += ba1[c];
    V[mat * CH + c] = acc;
  }
}

// K2: per-node tables T[mat][n][c] = f16( nf[n][:] . M[mat][:][c] + V[mat][c] )
// block = 256: c = tx&127, mat = tx>>7; 16 nodes per block (halves M re-reads
// vs 8/block). nf loads are block-uniform -> scalar unit; M loads coalesced.
__global__ __launch_bounds__(256) void k2_nodes(
    const float* __restrict__ nf, const float* __restrict__ M,
    const float* __restrict__ V, _Float16* __restrict__ T) {
  int tx = threadIdx.x;
  int c = tx & (CH - 1);
  int mat = tx >> 7;
  int n0 = blockIdx.x * 16;
  const float* Mm = M + mat * KN * CH + c;
  const float* r = nf + (size_t)n0 * KN;
  float acc[16];
#pragma unroll
  for (int j = 0; j < 16; ++j) acc[j] = 0.f;
#pragma unroll 2
  for (int k = 0; k < KN; ++k) {
    float m = Mm[k * CH];
#pragma unroll
    for (int j = 0; j < 16; ++j) acc[j] = fmaf(r[j * KN + k], m, acc[j]);
  }
  float v = V[mat * CH + c];
  _Float16* t = T + (size_t)mat * N_NODES * CH + c;
#pragma unroll
  for (int j = 0; j < 16; ++j)
    t[(size_t)(n0 + j) * CH] = (_Float16)(acc[j] + v);
}

// lrelu(s+d) . w over 8 channels, f32 accumulate via v_dot2_f32_f16
__device__ inline float edge_acc8(h8 s, h8 d, h8 w) {
  h8 t = s + d;                                  // 4x v_pk_add_f16
  h8 p = t * (_Float16)0.01f;                    // 4x v_pk_mul_f16
  h8 u = __builtin_elementwise_max(t, p);        // 4x v_pk_max_f16 (leaky relu)
  float acc = 0.f;
  acc = __builtin_amdgcn_fdot2(H2_OF(u, 0), H2_OF(w, 0), acc, false);
  acc = __builtin_amdgcn_fdot2(H2_OF(u, 1), H2_OF(w, 1), acc, false);
  acc = __builtin_amdgcn_fdot2(H2_OF(u, 2), H2_OF(w, 2), acc, false);
  acc = __builtin_amdgcn_fdot2(H2_OF(u, 3), H2_OF(w, 3), acc, false);
  return acc;
}

// K3: out[e] = b2 + sum_c w2[c] * lrelu(S[src[e]][c] + D[dst[e]][c])
// 16 lanes per edge-OCTET slot, 8 channels per lane, 8 edges per thread.
// 16 row-gathers in flight per thread (MLP); packed-butterfly reduction
// (15 shfl + 7 selects for 8 edges); lanes 0-7 do coalesced scalar stores.
__global__ __launch_bounds__(256) void k3_edges(
    const int* __restrict__ src, const int* __restrict__ dst,
    const _Float16* __restrict__ S, const _Float16* __restrict__ D,
    const _Float16* __restrict__ w2h, const float* __restrict__ b2,
    float* __restrict__ out) {
  int tid = blockIdx.x * 256 + threadIdx.x;
  int g = tid >> 4;             // edge-octet id, 0..N_EDGES/8-1
  int sub = tid & 15;
  int c0 = sub << 3;            // 8 channels per lane

  h8 w = *(const h8*)(w2h + c0);
  int4 sa = *(const int4*)(src + 8 * g);
  int4 sb = *(const int4*)(src + 8 * g + 4);
  int4 da = *(const int4*)(dst + 8 * g);
  int4 db = *(const int4*)(dst + 8 * g + 4);

  const _Float16* Sp = S + c0;
  const _Float16* Dp = D + c0;
  h8 s0 = *(const h8*)(Sp + ((size_t)sa.x << 7));
  h8 s1 = *(const h8*)(Sp + ((size_t)sa.y << 7));
  h8 s2 = *(const h8*)(Sp + ((size_t)sa.z << 7));
  h8 s3 = *(const h8*)(Sp + ((size_t)sa.w << 7));
  h8 s4 = *(const h8*)(Sp + ((size_t)sb.x << 7));
  h8 s5 = *(const h8*)(Sp + ((size_t)sb.y << 7));
  h8 s6 = *(const h8*)(Sp + ((size_t)sb.z << 7));
  h8 s7 = *(const h8*)(Sp + ((size_t)sb.w << 7));
  h8 d0 = *(const h8*)(Dp + ((size_t)da.x << 7));
  h8 d1 = *(const h8*)(Dp + ((size_t)da.y << 7));
  h8 d2 = *(const h8*)(Dp + ((size_t)da.z << 7));
  h8 d3 = *(const h8*)(Dp + ((size_t)da.w << 7));
  h8 d4 = *(const h8*)(Dp + ((size_t)db.x << 7));
  h8 d5 = *(const h8*)(Dp + ((size_t)db.y << 7));
  h8 d6 = *(const h8*)(Dp + ((size_t)db.z << 7));
  h8 d7 = *(const h8*)(Dp + ((size_t)db.w << 7));

  float a0 = edge_acc8(s0, d0, w);
  float a1 = edge_acc8(s1, d1, w);
  float a2 = edge_acc8(s2, d2, w);
  float a3 = edge_acc8(s3, d3, w);
  float a4 = edge_acc8(s4, d4, w);
  float a5 = edge_acc8(s5, d5, w);
  float a6 = edge_acc8(s6, d6, w);
  float a7 = edge_acc8(s7, d7, w);

  // packed butterfly: lane sub ends up holding the full sum for edge sub&7
  float r0 = a0 + __shfl_xor(a0, 1);
  float r1 = a1 + __shfl_xor(a1, 1);
  float r2 = a2 + __shfl_xor(a2, 1);
  float r3 = a3 + __shfl_xor(a3, 1);
  float r4 = a4 + __shfl_xor(a4, 1);
  float r5 = a5 + __shfl_xor(a5, 1);
  float r6 = a6 + __shfl_xor(a6, 1);
  float r7 = a7 + __shfl_xor(a7, 1);
  float b0 = (sub & 1) ? r1 : r0;
  float b1 = (sub & 1) ? r3 : r2;
  float b2v = (sub & 1) ? r5 : r4;
  float b3 = (sub & 1) ? r7 : r6;
  float t0 = b0 + __shfl_xor(b0, 2);
  float t1 = b1 + __shfl_xor(b1, 2);
  float t2 = b2v + __shfl_xor(b2v, 2);
  float t3 = b3 + __shfl_xor(b3, 2);
  float e0 = (sub & 2) ? t1 : t0;
  float e1 = (sub & 2) ? t3 : t2;
  float u0 = e0 + __shfl_xor(e0, 4);
  float u1 = e1 + __shfl_xor(e1, 4);
  float f = (sub & 4) ? u1 : u0;
  f += __shfl_xor(f, 8);

  if (sub < 8) out[8 * g + sub] = f + b2[0];
}

extern "C" void kernel_launch(void* const* d_in, const int* in_sizes, int n_in,
                              void* d_out, int out_size, void* d_ws, size_t ws_size,
                              hipStream_t stream) {
  const float* nf  = (const float*)d_in[0];
  // d_in[1] edge_feat, d_in[6] W_edge, d_in[7] b_edge: unused by the output
  const int*   src = (const int*)d_in[2];
  const int*   dst = (const int*)d_in[3];
  const float* Wn  = (const float*)d_in[4];
  const float* bn  = (const float*)d_in[5];
  const float* Wa1 = (const float*)d_in[8];
  const float* ba1 = (const float*)d_in[9];
  const float* Wa2 = (const float*)d_in[10];
  const float* ba2 = (const float*)d_in[11];
  float* out = (float*)d_out;

  char* ws = (char*)d_ws;
  float* M = (float*)ws;                                   // [2][118][128] f32
  float* V = (float*)(ws + 2 * KN * CH * sizeof(float));   // [2][128] f32
  _Float16* w2h = (_Float16*)(ws + (2 * KN * CH + 2 * CH) * sizeof(float));
  _Float16* T = (_Float16*)((char*)w2h + CH * sizeof(_Float16));
  _Float16* S = T;                                         // [10000][128] f16
  _Float16* D = T + (size_t)N_NODES * CH;                  // [10000][128] f16

  k1_weights<<<239, 128, 0, stream>>>(Wn, bn, Wa1, ba1, Wa2, M, V, w2h);
  k2_nodes<<<N_NODES / 16, 256, 0, stream>>>(nf, M, V, T);
  k3_edges<<<(N_EDGES / 8 * 16) / 256, 256, 0, stream>>>(src, dst, S, D, w2h, ba2, out);
}